// Round 9
// baseline (1335.310 us; speedup 1.0000x reference)
//
#include <hip/hip_runtime.h>
#include <stdint.h>

#define NV 163842
#define NTILE 1281          /* (NV+127)/128 */
#define EPSV 1e-5f
#define GRID_BLOCKS 512     /* 2 blocks/CU x 256 CU: LDS 2x52736=105KB << 160KB -> co-residency guaranteed */

using short8 = __attribute__((ext_vector_type(8))) short;   // 8 bf16 (4 VGPRs)
using f32x4  = __attribute__((ext_vector_type(4))) float;   // MFMA acc

static __device__ __forceinline__ unsigned short f2bf(float f) {
    union { float f; unsigned int i; } v; v.f = f;
    return (unsigned short)((v.i + 0x7FFFu + ((v.i >> 16) & 1u)) >> 16);  // RNE
}
static __device__ __forceinline__ void bf2x(unsigned int w, float& a, float& b) {
    union { unsigned int i; float f; } lo, hi;
    lo.i = w << 16; hi.i = w & 0xFFFF0000u;
    a = lo.f; b = hi.f;
}
static __device__ __forceinline__ unsigned int pack2(float a, float b) {
    union { float f; unsigned int i; } ua, ub; ua.f = a; ub.f = b;
    return __builtin_amdgcn_perm(ub.i + 0x8000u, ua.i + 0x8000u, 0x07060302);
}
static __device__ __forceinline__ void gl_lds16(const unsigned short* g, unsigned short* l) {
    __builtin_amdgcn_global_load_lds((__attribute__((address_space(1))) void*)g,
                                     (__attribute__((address_space(3))) void*)l, 16, 0, 0);
}

// ---- software grid barrier: monotonic generation, device-scope atomics.
//      Bounded spin -> on any co-residency failure we produce a WRONG ANSWER
//      (visible test fail) instead of a container hang. ----
static __device__ __forceinline__ void gridBarrier(unsigned int* BAR) {
    __threadfence();           // make this block's writes device-visible
    __syncthreads();
    if (threadIdx.x == 0) {
        unsigned int* cnt = BAR;
        unsigned int* gen = BAR + 1;
        unsigned int g = atomicAdd(gen, 0u);
        if (atomicAdd(cnt, 1u) == (unsigned)gridDim.x - 1u) {
            atomicExch(cnt, 0u);           // reset BEFORE release: no early arrivals possible
            atomicAdd(gen, 1u);            // release
        } else {
            int guard = 0;
            while (atomicAdd(gen, 0u) == g) {
                __builtin_amdgcn_s_sleep(32);
                if (++guard > 300000) break;    // ~0.2s escape hatch
            }
        }
    }
    __syncthreads();
    __threadfence();           // acquire: invalidate stale cached lines
}

struct MegaArgs {
    const float* x; const int* neigh;
    const float* G[4]; const float* B[4]; const float* W[4]; const float* WB[4];
    float* out;
    unsigned short* C; unsigned short* CN; unsigned short* WT; float* ACC;
    unsigned int* BAR;
};

// ---- norm phase (round-7 verified): BN+LeakyReLU once per vertex,
//      data-adaptive group skip with lane-parallel param compare. ----
static __device__ __forceinline__ void norm_phase(unsigned char* smem, int L,
                                                  const MegaArgs& a) {
    float* ssc = (float*)smem;
    float* ssh = ssc + 256;
    const int t = threadIdx.x;
    const int CIN = 64 * L;
    if (t < CIN) {
        float s = a.ACC[t], s2 = a.ACC[256 + t];
        float mu = s * (1.0f / NV);
        float var = fmaf(-mu, mu, s2 * (1.0f / NV));
        float sc = a.G[L - 1][t] * rsqrtf(var + EPSV);
        ssc[t] = sc;
        ssh[t] = a.B[L - 1][t] - mu * sc;
    }
    __syncthreads();
    const int lc = t & 63;
    for (int grp = 0; grp < L; ++grp) {
        bool need;
        if (grp == L - 1) {
            need = true;                       // newly produced group
        } else {
            int effL = grp;                    // layer whose params the group embodies
            for (int l = grp + 1; l <= L - 2; ++l) {
                int c = grp * 64 + lc;
                bool d = (a.G[l][c] != a.G[effL][c]) || (a.B[l][c] != a.B[effL][c]);
                if (__any(d)) effL = l;
            }
            int c = grp * 64 + lc;
            bool d = (a.G[L - 1][c] != a.G[effL][c]) || (a.B[L - 1][c] != a.B[effL][c]);
            need = __any(d);
        }
        if (!need) continue;
        const int total = NV * 8;
        for (int idx = blockIdx.x * 256 + t; idx < total; idx += gridDim.x * 256) {
            int v = idx >> 3;
            int ch = grp * 64 + (idx & 7) * 8;
            uint4 u = *(const uint4*)(a.C + (size_t)v * 256 + ch);
            unsigned int in[4] = {u.x, u.y, u.z, u.w}, o[4];
#pragma unroll
            for (int j = 0; j < 4; ++j) {
                float lo, hi; bf2x(in[j], lo, hi);
                float y0 = fmaf(lo, ssc[ch + 2 * j],     ssh[ch + 2 * j]);
                float y1 = fmaf(hi, ssc[ch + 2 * j + 1], ssh[ch + 2 * j + 1]);
                y0 = y0 > 0.f ? y0 : 0.2f * y0;
                y1 = y1 > 0.f ? y1 : 0.2f * y1;
                o[j] = pack2(y0, y1);
            }
            *(uint4*)(a.CN + (size_t)v * 256 + ch) = uint4{o[0], o[1], o[2], o[3]};
        }
    }
}

// ---- gg phase (round-3/7 verified body), grid-strided over tiles.
//      smem carve: sIdx[896]@0 | sA[2][8192]@3584 | sW[2][4096]@36352 (52736 B). ----
template<int CIN, int GRP, bool FINAL>
static __device__ __forceinline__ void gg_phase(unsigned char* smem, const MegaArgs& a,
                                                const unsigned short* WTl,
                                                const float* wb) {
    constexpr int KB = CIN / 64;
    constexpr int NC = 7 * KB;
    constexpr int K7 = 7 * CIN;
    int* sIdx = (int*)smem;
    auto sA = (unsigned short (*)[128 * 64])(smem + 3584);
    auto sW = (unsigned short (*)[64 * 64])(smem + 3584 + 32768);

    const int t = threadIdx.x;
    const int wv = t >> 6, lane = t & 63;
    const int m = lane & 15, quad = lane >> 4;
    const int rowin = lane >> 3, slot = lane & 7;
    const int sw = ((slot ^ rowin) * 8);

    for (int tile = blockIdx.x; tile < NTILE; tile += gridDim.x) {
        const int v0 = tile * 128;
        for (int q = t; q < 896; q += 256) {
            int gi = v0 * 7 + q;
            sIdx[q] = (gi < NV * 7) ? a.neigh[gi] : 0;
        }
        f32x4 acc[2][4];
#pragma unroll
        for (int i = 0; i < 2; ++i)
#pragma unroll
            for (int j = 0; j < 4; ++j) acc[i][j] = f32x4{0.f, 0.f, 0.f, 0.f};
        __syncthreads();   // sIdx ready; also protects prev tile's red reads

        auto issue_stage = [&](int r, int kb, int c, int b) {
#pragma unroll
            for (int i = 0; i < 4; ++i) {
                int gidx = sIdx[(wv * 32 + i * 8 + rowin) * 7 + r];
                gl_lds16(a.CN + (size_t)gidx * 256 + kb * 64 + sw, &sA[b][(wv * 32 + i * 8) * 64]);
            }
#pragma unroll
            for (int j = 0; j < 2; ++j) {
                int n = wv * 16 + j * 8 + rowin;
                gl_lds16(WTl + (size_t)n * K7 + c * 64 + sw, &sW[b][(wv * 16 + j * 8) * 64]);
            }
        };
        auto compute = [&](int b) {
            __builtin_amdgcn_s_setprio(1);
#pragma unroll
            for (int s = 0; s < 2; ++s) {
                const int sx = ((s * 4 + quad) ^ (m & 7)) * 8;
                short8 af0 = *(const short8*)(&sA[b][(wv * 32 + m) * 64 + sx]);
                short8 af1 = *(const short8*)(&sA[b][(wv * 32 + 16 + m) * 64 + sx]);
#pragma unroll
                for (int ct = 0; ct < 4; ++ct) {
                    short8 bf = *(const short8*)(&sW[b][(ct * 16 + m) * 64 + sx]);
                    acc[0][ct] = __builtin_amdgcn_mfma_f32_16x16x32_bf16(af0, bf, acc[0][ct], 0, 0, 0);
                    acc[1][ct] = __builtin_amdgcn_mfma_f32_16x16x32_bf16(af1, bf, acc[1][ct], 0, 0, 0);
                }
            }
            __builtin_amdgcn_s_setprio(0);
        };

        issue_stage(0, 0, 0, 0);
        __syncthreads();
        int r = 0, kb = 0, buf = 0;
        for (int c = 0; c < NC - 1; ++c) {
            int kb1 = kb + 1, r1 = r;
            if (kb1 == KB) { kb1 = 0; r1 = r + 1; }
            issue_stage(r1, kb1, c + 1, buf ^ 1);   // in flight across compute
            compute(buf);
            __syncthreads();                        // drain: c+1 resident, buf reusable
            r = r1; kb = kb1; buf ^= 1;
        }
        compute(buf);
        __syncthreads();   // before reusing sA as reduction scratch

        float bsum[4]  = {0.f, 0.f, 0.f, 0.f};
        float b2sum[4] = {0.f, 0.f, 0.f, 0.f};
#pragma unroll
        for (int mt = 0; mt < 2; ++mt) {
#pragma unroll
            for (int ct = 0; ct < 4; ++ct) {
                int col = ct * 16 + m;
                float bv = wb[col];
#pragma unroll
                for (int j = 0; j < 4; ++j) {
                    int vr = v0 + wv * 32 + mt * 16 + quad * 4 + j;
                    float val = acc[mt][ct][j] + bv;
                    if (vr < NV) {
                        if (FINAL) {
                            a.out[(size_t)vr * 64 + col] = val;
                        } else {
                            a.C[(size_t)vr * 256 + GRP * 64 + col] = f2bf(val);
                            bsum[ct] += val; b2sum[ct] += val * val;
                        }
                    }
                }
            }
        }
        if (!FINAL) {
#pragma unroll
            for (int ct = 0; ct < 4; ++ct) {
                bsum[ct]  += __shfl_xor(bsum[ct], 16);
                bsum[ct]  += __shfl_xor(bsum[ct], 32);
                b2sum[ct] += __shfl_xor(b2sum[ct], 16);
                b2sum[ct] += __shfl_xor(b2sum[ct], 32);
            }
            float* red = (float*)&sA[0][0];
            if (quad == 0) {
#pragma unroll
                for (int ct = 0; ct < 4; ++ct) {
                    red[wv * 128 + ct * 16 + m]       = bsum[ct];
                    red[512 + wv * 128 + ct * 16 + m] = b2sum[ct];
                }
            }
            __syncthreads();
            if (t < 128) {
                int c = t & 63, which = t >> 6;
                float v = red[which * 512 + c] + red[which * 512 + 128 + c] +
                          red[which * 512 + 256 + c] + red[which * 512 + 384 + c];
                atomicAdd(&a.ACC[which * 256 + GRP * 64 + c], v);
            }
        }
    }
}

// ---- whole pipeline in ONE normal-launch persistent kernel; 8 software grid
//      barriers replace ~10 serialized dispatch boundaries (~20 us each). ----
__global__ __launch_bounds__(256, 2) void k_mega(MegaArgs a) {
    __shared__ __align__(16) unsigned char smem[52736];
    const int t = threadIdx.x;

    // ---- phase 1: WT transpose + cast x->bf16 + stats (ACC pre-zeroed by memset) ----
    for (int j = blockIdx.x * 256 + t; j < 286720; j += gridDim.x * 256) {
        const float* W; int jj, K7;
        if (j < 28672)       { W = a.W[0]; jj = j;          K7 = 448;  }
        else if (j < 86016)  { W = a.W[1]; jj = j - 28672;  K7 = 896;  }
        else if (j < 172032) { W = a.W[2]; jj = j - 86016;  K7 = 1344; }
        else                 { W = a.W[3]; jj = j - 172032; K7 = 1792; }
        int n = jj / K7, k = jj - n * K7;
        a.WT[j] = f2bf(W[(size_t)k * 64 + n]);
    }
    {
        float* red = (float*)smem;
        const int wv = t >> 6, lane = t & 63;
        float statAcc = 0.f;
        for (int vb = blockIdx.x; vb < 2561; vb += gridDim.x) {
            const int v = vb * 64 + (t >> 2);
            const int c0 = (t & 3) * 16;
            float f[16];
            const bool valid = v < NV;
            if (valid) {
                const float4* p = (const float4*)(a.x + (size_t)v * 64 + c0);
#pragma unroll
                for (int i = 0; i < 4; ++i) {
                    float4 q = p[i];
                    f[i * 4 + 0] = q.x; f[i * 4 + 1] = q.y; f[i * 4 + 2] = q.z; f[i * 4 + 3] = q.w;
                }
                unsigned int o[8];
#pragma unroll
                for (int i = 0; i < 8; ++i)
                    o[i] = ((unsigned int)f2bf(f[2 * i])) | (((unsigned int)f2bf(f[2 * i + 1])) << 16);
                uint4* dst = (uint4*)(a.C + (size_t)v * 256 + c0);
                dst[0] = uint4{o[0], o[1], o[2], o[3]};
                dst[1] = uint4{o[4], o[5], o[6], o[7]};
            } else {
#pragma unroll
                for (int i = 0; i < 16; ++i) f[i] = 0.f;
            }
            float s[16], s2[16];
#pragma unroll
            for (int i = 0; i < 16; ++i) { s[i] = f[i]; s2[i] = f[i] * f[i]; }
#pragma unroll
            for (int mask = 4; mask <= 32; mask <<= 1) {
#pragma unroll
                for (int i = 0; i < 16; ++i) {
                    s[i]  += __shfl_xor(s[i],  mask);
                    s2[i] += __shfl_xor(s2[i], mask);
                }
            }
            if ((lane >> 2) == 0) {
                int cb = (lane & 3) * 16;
#pragma unroll
                for (int i = 0; i < 16; ++i) {
                    red[wv * 128 + cb + i]      = s[i];
                    red[wv * 128 + 64 + cb + i] = s2[i];
                }
            }
            __syncthreads();
            if (t < 128) statAcc += red[t] + red[128 + t] + red[256 + t] + red[384 + t];
            __syncthreads();   // red reusable next vb
        }
        if (t < 128) atomicAdd(&a.ACC[(t >> 6) * 256 + (t & 63)], statAcc);
    }
    gridBarrier(a.BAR);   // #1: C, WT, x-stats complete

    norm_phase(smem, 1, a);
    gridBarrier(a.BAR);   // #2
    gg_phase< 64, 1, false>(smem, a, a.WT,          a.WB[0]);
    gridBarrier(a.BAR);   // #3: x1 + its stats complete
    norm_phase(smem, 2, a);
    gridBarrier(a.BAR);   // #4
    gg_phase<128, 2, false>(smem, a, a.WT + 28672,  a.WB[1]);
    gridBarrier(a.BAR);   // #5
    norm_phase(smem, 3, a);
    gridBarrier(a.BAR);   // #6
    gg_phase<192, 3, false>(smem, a, a.WT + 86016,  a.WB[2]);
    gridBarrier(a.BAR);   // #7
    norm_phase(smem, 4, a);
    gridBarrier(a.BAR);   // #8
    gg_phase<256, 0, true >(smem, a, a.WT + 172032, a.WB[3]);
}

extern "C" void kernel_launch(void* const* d_in, const int* in_sizes, int n_in,
                              void* d_out, int out_size, void* d_ws, size_t ws_size,
                              hipStream_t stream) {
    char* ws = (char*)d_ws;
    size_t off = 0;
    unsigned short* C  = (unsigned short*)(ws + off); off += (size_t)NV * 256 * 2;
    unsigned short* CN = (unsigned short*)(ws + off); off += (size_t)NV * 256 * 2;
    unsigned short* WT = (unsigned short*)(ws + off); off += (size_t)286720 * 2;
    float* ACC         = (float*)(ws + off);          off += 512 * 4;
    unsigned int* BAR  = (unsigned int*)(ws + off);   off += 64;

    MegaArgs ma;
    ma.x     = (const float*)d_in[0];
    ma.neigh = (const int*)d_in[1];
    for (int i = 0; i < 4; ++i) {
        ma.G[i]  = (const float*)d_in[2 + 4 * i];
        ma.B[i]  = (const float*)d_in[3 + 4 * i];
        ma.W[i]  = (const float*)d_in[4 + 4 * i];
        ma.WB[i] = (const float*)d_in[5 + 4 * i];
    }
    ma.out = (float*)d_out;
    ma.C = C; ma.CN = CN; ma.WT = WT; ma.ACC = ACC; ma.BAR = BAR;

    // zero ACC (2048 B) + barrier state (cnt,gen) in one memset node
    hipMemsetAsync(ACC, 0, 512 * sizeof(float) + 64, stream);
    k_mega<<<GRID_BLOCKS, 256, 0, stream>>>(ma);
}